// Round 4
// baseline (327.208 us; speedup 1.0000x reference)
//
#include <hip/hip_runtime.h>
#include <hip/hip_bf16.h>

#define B_ 4
#define S_ 2048
#define D_ 1024
#define H_ 16
#define HD_ 64

typedef __attribute__((ext_vector_type(8))) short bf16x8;
typedef __attribute__((ext_vector_type(4))) short bf16x4;
typedef __attribute__((ext_vector_type(4))) float f32x4;

// legacy-K bf16 MFMA (v_mfma_f32_16x16x16_bf16): clang spelling is the
// gfx90a-era "_1k" name; valid on gfx950 (cdna4_isa.md §10). Do NOT guard
// with __has_builtin -- it is target-sensitive and breaks the HIP host pass.
#define MFMA16(a, b, c) __builtin_amdgcn_mfma_f32_16x16x16bf16_1k(a, b, c, 0, 0, 0)

__device__ __forceinline__ float fast_exp2(float x) {
#if __has_builtin(__builtin_amdgcn_exp2f)
  return __builtin_amdgcn_exp2f(x);
#else
  return exp2f(x);
#endif
}

__device__ __forceinline__ float fast_rcp(float x) {
#if __has_builtin(__builtin_amdgcn_rcpf)
  return __builtin_amdgcn_rcpf(x);
#else
  return 1.0f / x;
#endif
}

__device__ __forceinline__ short f2bf(float x) {
  union { float f; unsigned u; } v; v.f = x;
  unsigned r = (v.u + 0x7fffu + ((v.u >> 16) & 1u)) >> 16;
  return (short)(r & 0xffffu);
}

// truncate-pack two fp32 -> packed bf16 pair (bias cancels in softmax ratio
// because lsum is computed from the SAME truncated values via MFMA-ones)
__device__ __forceinline__ unsigned pack_trunc(float a, float b) {
  union { float f; unsigned u; } ua, ub; ua.f = a; ub.f = b;
  return (ub.u & 0xffff0000u) | (ua.u >> 16);
}

// ---------------- Kernel 0: convert Wo (fp32 -> bf16) ----------------
__global__ __launch_bounds__(256) void wo_convert(const float* __restrict__ Wo,
                                                  short* __restrict__ wob) {
  int i = blockIdx.x * blockDim.x + threadIdx.x;
  const float4* src = (const float4*)Wo + i * 2;
  float4 a = src[0], b = src[1];
  bf16x8 o;
  o[0] = f2bf(a.x); o[1] = f2bf(a.y); o[2] = f2bf(a.z); o[3] = f2bf(a.w);
  o[4] = f2bf(b.x); o[5] = f2bf(b.y); o[6] = f2bf(b.z); o[7] = f2bf(b.w);
  ((bf16x8*)wob)[i] = o;
}

// ---------------- Kernel 1: QKV projections via MFMA ----------------
__global__ __launch_bounds__(256) void qkv_proj2(
    const float* __restrict__ inpV, const float* __restrict__ inpK,
    const float* __restrict__ inpQ, const float* __restrict__ Wv,
    const float* __restrict__ Wk, const float* __restrict__ Wq,
    short* __restrict__ vt, short* __restrict__ kp, short* __restrict__ qp) {
  __shared__ bf16x8 xbuf[1024];  // 128 rows x 8 groups (16KB), g^=row&7
  __shared__ bf16x8 wbuf[512];   // 64 rows x 8 groups (8KB), g^=row&7
  int bid = blockIdx.x;
  int t = bid >> 10;           // 1024 blocks per tensor
  int bh = (bid >> 4) & 63;    // b*16+h
  int st = bid & 15;
  int b = bh >> 4, h = bh & 15;
  int s0 = st * 128;
  int tid = threadIdx.x, wave = tid >> 6, lane = tid & 63;
  int quad = lane >> 4, l15 = lane & 15;
  const float* inp = (t == 0) ? inpV : (t == 1) ? inpK : inpQ;
  const float* W = (t == 0) ? Wv : (t == 1) ? Wk : Wq;
  // fold score scale AND log2(e) into Wq (attention uses exp2)
  float wscale = (t == 2) ? (0.03125f * 1.4426950408889634f) : 1.0f;

#pragma unroll
  for (int u = 0; u < 2; ++u) {
    int slot = tid + u * 256;
    int row = slot >> 3, g = slot & 7;
    const float4* wp = (const float4*)(W + row * 64 + g * 8);
    float4 w0 = wp[0], w1 = wp[1];
    bf16x8 o;
    o[0] = f2bf(w0.x * wscale); o[1] = f2bf(w0.y * wscale);
    o[2] = f2bf(w0.z * wscale); o[3] = f2bf(w0.w * wscale);
    o[4] = f2bf(w1.x * wscale); o[5] = f2bf(w1.y * wscale);
    o[6] = f2bf(w1.z * wscale); o[7] = f2bf(w1.w * wscale);
    wbuf[row * 8 + (g ^ (row & 7))] = o;
  }
  const float* xg = inp + (b * S_ + s0) * D_ + h * HD_;
#pragma unroll
  for (int u = 0; u < 4; ++u) {
    int slot = tid + u * 256;
    int row = slot >> 3, g = slot & 7;
    const float4* xp = (const float4*)(xg + row * D_ + g * 8);
    float4 x0 = xp[0], x1 = xp[1];
    bf16x8 o;
    o[0] = f2bf(x0.x); o[1] = f2bf(x0.y); o[2] = f2bf(x0.z); o[3] = f2bf(x0.w);
    o[4] = f2bf(x1.x); o[5] = f2bf(x1.y); o[6] = f2bf(x1.z); o[7] = f2bf(x1.w);
    xbuf[row * 8 + (g ^ (row & 7))] = o;
  }
  __syncthreads();

  if (t == 0) {
    f32x4 acc[4][2];
#pragma unroll
    for (int mt = 0; mt < 4; mt++)
#pragma unroll
      for (int nt = 0; nt < 2; nt++) { acc[mt][nt][0]=0.f; acc[mt][nt][1]=0.f; acc[mt][nt][2]=0.f; acc[mt][nt][3]=0.f; }
#pragma unroll
    for (int ks = 0; ks < 2; ++ks) {
      bf16x8 af[4], bfr[2];
#pragma unroll
      for (int mt = 0; mt < 4; ++mt) {
        int row = mt * 16 + l15;
        af[mt] = wbuf[row * 8 + ((ks * 4 + quad) ^ (row & 7))];
      }
#pragma unroll
      for (int nt = 0; nt < 2; ++nt) {
        int row = wave * 32 + nt * 16 + l15;
        bfr[nt] = xbuf[row * 8 + ((ks * 4 + quad) ^ (row & 7))];
      }
#pragma unroll
      for (int mt = 0; mt < 4; ++mt)
#pragma unroll
        for (int nt = 0; nt < 2; ++nt)
          acc[mt][nt] = __builtin_amdgcn_mfma_f32_16x16x32_bf16(
              af[mt], bfr[nt], acc[mt][nt], 0, 0, 0);
    }
    short* vb = vt + (bh * 64) * S_ + s0 + wave * 32;
#pragma unroll
    for (int mt = 0; mt < 4; ++mt)
#pragma unroll
      for (int nt = 0; nt < 2; ++nt)
#pragma unroll
        for (int r = 0; r < 4; ++r) {
          int e = mt * 16 + quad * 4 + r;
          int s = nt * 16 + l15;
          vb[e * S_ + s] = f2bf(acc[mt][nt][r]);
        }
  } else {
    f32x4 acc[2][4];
#pragma unroll
    for (int mt = 0; mt < 2; mt++)
#pragma unroll
      for (int nt = 0; nt < 4; nt++) { acc[mt][nt][0]=0.f; acc[mt][nt][1]=0.f; acc[mt][nt][2]=0.f; acc[mt][nt][3]=0.f; }
#pragma unroll
    for (int ks = 0; ks < 2; ++ks) {
      bf16x8 af[2], bfr[4];
#pragma unroll
      for (int mt = 0; mt < 2; ++mt) {
        int row = wave * 32 + mt * 16 + l15;
        af[mt] = xbuf[row * 8 + ((ks * 4 + quad) ^ (row & 7))];
      }
#pragma unroll
      for (int nt = 0; nt < 4; ++nt) {
        int row = nt * 16 + l15;
        bfr[nt] = wbuf[row * 8 + ((ks * 4 + quad) ^ (row & 7))];
      }
#pragma unroll
      for (int mt = 0; mt < 2; ++mt)
#pragma unroll
        for (int nt = 0; nt < 4; ++nt)
          acc[mt][nt] = __builtin_amdgcn_mfma_f32_16x16x32_bf16(
              af[mt], bfr[nt], acc[mt][nt], 0, 0, 0);
    }
    short* ob = ((t == 1) ? kp : qp) + (bh * S_ + s0 + wave * 32) * 64;
#pragma unroll
    for (int mt = 0; mt < 2; ++mt)
#pragma unroll
      for (int nt = 0; nt < 4; ++nt)
#pragma unroll
        for (int r = 0; r < 4; ++r) {
          int s = mt * 16 + quad * 4 + r;
          int e = nt * 16 + l15;
          ob[s * 64 + e] = f2bf(acc[mt][nt][r]);
        }
  }
}

// ---------------- Kernel 2: fused attention (S^T trick, no P LDS) --------
// Block = (b,h) x 128 q-rows; 4 waves x 32 q. S^T = K*Q^T so the 16x16 C
// regs of P feed mfma_16x16x16 A-frags directly. lsum via MFMA ones-column.
__global__ __launch_bounds__(256) void attention(
    const short* __restrict__ qp, const short* __restrict__ kp,
    const short* __restrict__ vt, short* __restrict__ ao) {
  __shared__ bf16x8 kbuf[512];  // 64 krows x 8 groups (8KB)
  __shared__ bf16x8 vbuf[512];  // 64 drows x 8 groups (8KB)
  int bid = blockIdx.x;
  int qt = bid >> 6;   // 16 q-tiles of 128
  int bh = bid & 63;   // XCD = bid%8 = bh%8 -> whole head on one XCD
  int tid = threadIdx.x, wave = tid >> 6, lane = tid & 63;
  int quad = lane >> 4, l15 = lane & 15;

  // Q B-frags: 2 q-groups x (k 0..31 | 32..63), loaded once
  const short* qb = qp + (bh * S_ + qt * 128 + wave * 32 + l15) * 64;
  bf16x8 bq[2][2];
  bq[0][0] = *(const bf16x8*)(qb + quad * 8);
  bq[0][1] = *(const bf16x8*)(qb + 32 + quad * 8);
  bq[1][0] = *(const bf16x8*)(qb + 1024 + quad * 8);
  bq[1][1] = *(const bf16x8*)(qb + 1024 + 32 + quad * 8);

  f32x4 o[2][4];
#pragma unroll
  for (int g = 0; g < 2; g++)
#pragma unroll
    for (int dt = 0; dt < 4; dt++) { o[g][dt][0]=0.f; o[g][dt][1]=0.f; o[g][dt][2]=0.f; o[g][dt][3]=0.f; }
  f32x4 lacc[2];
  lacc[0][0]=0.f; lacc[0][1]=0.f; lacc[0][2]=0.f; lacc[0][3]=0.f;
  lacc[1][0]=0.f; lacc[1][1]=0.f; lacc[1][2]=0.f; lacc[1][3]=0.f;

  // ones-column B-frag: B[k][0]=1.0 (lane l15==0), rest 0
  short one_bf = (short)0x3F80;
  bf16x4 ones;
  ones[0] = (l15 == 0) ? one_bf : (short)0;
  ones[1] = ones[0]; ones[2] = ones[0]; ones[3] = ones[0];

  const short* kg = kp + bh * S_ * 64;
  const short* vg = vt + bh * 64 * S_;

  for (int kt = 0; kt < 32; ++kt) {
    __syncthreads();
#pragma unroll
    for (int u = 0; u < 2; ++u) {
      int slot = tid + u * 256;
      int row = slot >> 3, gp = slot & 7, g = gp ^ (row & 7);
      kbuf[slot] = *(const bf16x8*)(kg + (kt * 64 + row) * 64 + g * 8);
      vbuf[slot] = *(const bf16x8*)(vg + row * S_ + kt * 64 + g * 8);
    }
    __syncthreads();

    // ---- S^T = K*Q^T, then P = exp2(S^T) packed as PV A-frags ----
    bf16x4 pk[2][4];
#pragma unroll
    for (int nt = 0; nt < 4; ++nt) {
      int krow = nt * 16 + l15;
      bf16x8 ak0 = kbuf[krow * 8 + ((0 + quad) ^ (krow & 7))];
      bf16x8 ak1 = kbuf[krow * 8 + ((4 + quad) ^ (krow & 7))];
      f32x4 c0, c1;
      c0[0]=0.f; c0[1]=0.f; c0[2]=0.f; c0[3]=0.f;
      c1[0]=0.f; c1[1]=0.f; c1[2]=0.f; c1[3]=0.f;
      c0 = __builtin_amdgcn_mfma_f32_16x16x32_bf16(ak0, bq[0][0], c0, 0, 0, 0);
      c1 = __builtin_amdgcn_mfma_f32_16x16x32_bf16(ak0, bq[1][0], c1, 0, 0, 0);
      c0 = __builtin_amdgcn_mfma_f32_16x16x32_bf16(ak1, bq[0][1], c0, 0, 0, 0);
      c1 = __builtin_amdgcn_mfma_f32_16x16x32_bf16(ak1, bq[1][1], c1, 0, 0, 0);
      float e00 = fast_exp2(c0[0]), e01 = fast_exp2(c0[1]);
      float e02 = fast_exp2(c0[2]), e03 = fast_exp2(c0[3]);
      float e10 = fast_exp2(c1[0]), e11 = fast_exp2(c1[1]);
      float e12 = fast_exp2(c1[2]), e13 = fast_exp2(c1[3]);
      union { bf16x4 v; unsigned u[2]; } p0, p1;
      p0.u[0] = pack_trunc(e00, e01); p0.u[1] = pack_trunc(e02, e03);
      p1.u[0] = pack_trunc(e10, e11); p1.u[1] = pack_trunc(e12, e13);
      pk[0][nt] = p0.v; pk[1][nt] = p1.v;
    }
    // ---- PV + lsum (k-chunk c = 16 keys) ----
#pragma unroll
    for (int c = 0; c < 4; ++c) {
      lacc[0] = MFMA16(pk[0][c], ones, lacc[0]);
      lacc[1] = MFMA16(pk[1][c], ones, lacc[1]);
#pragma unroll
      for (int dt = 0; dt < 4; ++dt) {
        int d = dt * 16 + l15;
        int g0 = 2 * c + (quad >> 1);
        const short* vrow = (const short*)&vbuf[d * 8 + (g0 ^ (d & 7))];
        bf16x4 bv = *(const bf16x4*)(vrow + (quad & 1) * 4);
        o[0][dt] = MFMA16(pk[0][c], bv, o[0][dt]);
        o[1][dt] = MFMA16(pk[1][c], bv, o[1][dt]);
      }
    }
  }

  // epilogue: lsum[q=quad*4+r] sits at lane (quad, l15==0), reg r
  int b = bh >> 4, h = bh & 15;
#pragma unroll
  for (int g = 0; g < 2; ++g) {
    float inv[4];
#pragma unroll
    for (int r = 0; r < 4; ++r) {
      float ls = __shfl(lacc[g][r], lane & 48, 64);
      inv[r] = fast_rcp(ls);
    }
#pragma unroll
    for (int dt = 0; dt < 4; ++dt)
#pragma unroll
      for (int r = 0; r < 4; ++r) {
        int srow = qt * 128 + wave * 32 + g * 16 + quad * 4 + r;
        ao[(b * S_ + srow) * D_ + h * 64 + dt * 16 + l15] =
            f2bf(o[g][dt][r] * inv[r]);
      }
  }
}

// ---------------- Kernel 3: output projection GEMM + bias ----------------
__global__ __launch_bounds__(256) void outproj(const short* __restrict__ A,
                                               const short* __restrict__ Bw,
                                               const float* __restrict__ bo,
                                               float* __restrict__ out) {
  __shared__ bf16x8 sa[1024];
  __shared__ bf16x8 sb[1024];
  int bid = blockIdx.x;
  int m0 = (bid >> 3) * 128, n0 = (bid & 7) * 128;
  int tid = threadIdx.x, wave = tid >> 6, lane = tid & 63;
  int quad = lane >> 4, l15 = lane & 15;
  int wm = (wave >> 1) * 64, wn = (wave & 1) * 64;
  f32x4 acc[4][4];
#pragma unroll
  for (int mt = 0; mt < 4; mt++)
#pragma unroll
    for (int nt = 0; nt < 4; nt++) { acc[mt][nt][0]=0.f; acc[mt][nt][1]=0.f; acc[mt][nt][2]=0.f; acc[mt][nt][3]=0.f; }

  for (int k0 = 0; k0 < 1024; k0 += 64) {
    __syncthreads();
#pragma unroll
    for (int u = 0; u < 4; ++u) {
      int slot = tid + u * 256;
      int row = slot >> 3, gp = slot & 7, g = gp ^ (row & 7);
      sa[slot] = *(const bf16x8*)(A + (m0 + row) * 1024 + k0 + g * 8);
      sb[slot] = *(const bf16x8*)(Bw + (n0 + row) * 1024 + k0 + g * 8);
    }
    __syncthreads();
#pragma unroll
    for (int ks = 0; ks < 2; ++ks) {
      bf16x8 af[4], bf[4];
#pragma unroll
      for (int mt = 0; mt < 4; ++mt) {
        int row = wm + mt * 16 + l15;
        af[mt] = sa[row * 8 + ((ks * 4 + quad) ^ (row & 7))];
      }
#pragma unroll
      for (int nt = 0; nt < 4; ++nt) {
        int row = wn + nt * 16 + l15;
        bf[nt] = sb[row * 8 + ((ks * 4 + quad) ^ (row & 7))];
      }
#pragma unroll
      for (int mt = 0; mt < 4; ++mt)
#pragma unroll
        for (int nt = 0; nt < 4; ++nt)
          acc[mt][nt] = __builtin_amdgcn_mfma_f32_16x16x32_bf16(
              af[mt], bf[nt], acc[mt][nt], 0, 0, 0);
    }
  }
#pragma unroll
  for (int nt = 0; nt < 4; ++nt) {
    int n = n0 + wn + nt * 16 + l15;
    float bov = bo[n];
#pragma unroll
    for (int mt = 0; mt < 4; ++mt)
#pragma unroll
      for (int r = 0; r < 4; r++) {
        int m = m0 + wm + mt * 16 + quad * 4 + r;
        out[m * 1024 + n] = acc[mt][nt][r] + bov;
      }
  }
}

extern "C" void kernel_launch(void* const* d_in, const int* in_sizes, int n_in,
                              void* d_out, int out_size, void* d_ws,
                              size_t ws_size, hipStream_t stream) {
  const float* inpV = (const float*)d_in[0];
  const float* inpK = (const float*)d_in[1];
  const float* inpQ = (const float*)d_in[2];
  const float* Wv = (const float*)d_in[3];
  const float* Wk = (const float*)d_in[4];
  const float* Wq = (const float*)d_in[5];
  const float* Wo = (const float*)d_in[6];
  const float* bo = (const float*)d_in[7];
  float* out = (float*)d_out;

  char* ws = (char*)d_ws;
  short* vt = (short*)(ws);                       // 16MB  [B,H,64,S]
  short* kp = (short*)(ws + (16u << 20));         // 16MB  [B,H,S,64]
  short* qp = (short*)(ws + (32u << 20));         // 16MB  [B,H,S,64]
  short* ao = (short*)(ws + (48u << 20));         // 16MB  [B*S, D] bf16
  short* wob = (short*)(ws + (64u << 20));        // 2MB   Wo bf16

  wo_convert<<<dim3(512), dim3(256), 0, stream>>>(Wo, wob);
  qkv_proj2<<<dim3(3072), dim3(256), 0, stream>>>(inpV, inpK, inpQ, Wv, Wk, Wq,
                                                  vt, kp, qp);
  attention<<<dim3(1024), dim3(256), 0, stream>>>(qp, kp, vt, ao);
  outproj<<<dim3(512), dim3(256), 0, stream>>>(ao, wob, bo, out);
}

// Round 5
// 296.490 us; speedup vs baseline: 1.1036x; 1.1036x over previous
//
#include <hip/hip_runtime.h>
#include <hip/hip_bf16.h>

#define B_ 4
#define S_ 2048
#define D_ 1024
#define H_ 16
#define HD_ 64

typedef __attribute__((ext_vector_type(8))) short bf16x8;
typedef __attribute__((ext_vector_type(4))) short bf16x4;
typedef __attribute__((ext_vector_type(4))) float f32x4;

// legacy-K bf16 MFMA (v_mfma_f32_16x16x16_bf16): clang spelling is the
// gfx90a-era "_1k" name; valid on gfx950. NOT __has_builtin-guarded (that
// macro is target-sensitive and breaks the HIP host pass).
#define MFMA16(a, b, c) __builtin_amdgcn_mfma_f32_16x16x16bf16_1k(a, b, c, 0, 0, 0)

__device__ __forceinline__ float fast_exp2(float x) {
#if __has_builtin(__builtin_amdgcn_exp2f)
  return __builtin_amdgcn_exp2f(x);
#else
  return exp2f(x);
#endif
}

__device__ __forceinline__ float fast_rcp(float x) {
#if __has_builtin(__builtin_amdgcn_rcpf)
  return __builtin_amdgcn_rcpf(x);
#else
  return 1.0f / x;
#endif
}

__device__ __forceinline__ short f2bf(float x) {
  union { float f; unsigned u; } v; v.f = x;
  unsigned r = (v.u + 0x7fffu + ((v.u >> 16) & 1u)) >> 16;
  return (short)(r & 0xffffu);
}

__device__ __forceinline__ unsigned pack_trunc(float a, float b) {
  union { float f; unsigned u; } ua, ub; ua.f = a; ub.f = b;
  return (ub.u & 0xffff0000u) | (ua.u >> 16);
}

// async global->LDS DMA, 16 B per lane. LDS dest must be wave-uniform base +
// lane*16 -- all call sites use slot = tid + u*256 (lane-contiguous). [m97]
__device__ __forceinline__ void gl_lds16(const short* g, void* l) {
  __builtin_amdgcn_global_load_lds(
      (const __attribute__((address_space(1))) unsigned*)(const void*)g,
      (__attribute__((address_space(3))) unsigned*)l, 16, 0, 0);
}

// ---------------- Kernel 0: convert Wo (fp32 -> bf16) ----------------
__global__ __launch_bounds__(256) void wo_convert(const float* __restrict__ Wo,
                                                  short* __restrict__ wob) {
  int i = blockIdx.x * blockDim.x + threadIdx.x;
  const float4* src = (const float4*)Wo + i * 2;
  float4 a = src[0], b = src[1];
  bf16x8 o;
  o[0] = f2bf(a.x); o[1] = f2bf(a.y); o[2] = f2bf(a.z); o[3] = f2bf(a.w);
  o[4] = f2bf(b.x); o[5] = f2bf(b.y); o[6] = f2bf(b.z); o[7] = f2bf(b.w);
  ((bf16x8*)wob)[i] = o;
}

// ---------------- Kernel 1: QKV projections via MFMA ----------------
__global__ __launch_bounds__(256) void qkv_proj2(
    const float* __restrict__ inpV, const float* __restrict__ inpK,
    const float* __restrict__ inpQ, const float* __restrict__ Wv,
    const float* __restrict__ Wk, const float* __restrict__ Wq,
    short* __restrict__ vt, short* __restrict__ kp, short* __restrict__ qp) {
  __shared__ bf16x8 xbuf[1024];  // 128 rows x 8 groups (16KB), g^=row&7
  __shared__ bf16x8 wbuf[512];   // 64 rows x 8 groups (8KB), g^=row&7
  int bid = blockIdx.x;
  int t = bid >> 10;           // 1024 blocks per tensor
  int bh = (bid >> 4) & 63;    // b*16+h
  int st = bid & 15;
  int b = bh >> 4, h = bh & 15;
  int s0 = st * 128;
  int tid = threadIdx.x, wave = tid >> 6, lane = tid & 63;
  int quad = lane >> 4, l15 = lane & 15;
  const float* inp = (t == 0) ? inpV : (t == 1) ? inpK : inpQ;
  const float* W = (t == 0) ? Wv : (t == 1) ? Wk : Wq;
  // fold score scale AND log2(e) into Wq (attention uses exp2)
  float wscale = (t == 2) ? (0.03125f * 1.4426950408889634f) : 1.0f;

#pragma unroll
  for (int u = 0; u < 2; ++u) {
    int slot = tid + u * 256;
    int row = slot >> 3, g = slot & 7;
    const float4* wp = (const float4*)(W + row * 64 + g * 8);
    float4 w0 = wp[0], w1 = wp[1];
    bf16x8 o;
    o[0] = f2bf(w0.x * wscale); o[1] = f2bf(w0.y * wscale);
    o[2] = f2bf(w0.z * wscale); o[3] = f2bf(w0.w * wscale);
    o[4] = f2bf(w1.x * wscale); o[5] = f2bf(w1.y * wscale);
    o[6] = f2bf(w1.z * wscale); o[7] = f2bf(w1.w * wscale);
    wbuf[row * 8 + (g ^ (row & 7))] = o;
  }
  const float* xg = inp + (b * S_ + s0) * D_ + h * HD_;
#pragma unroll
  for (int u = 0; u < 4; ++u) {
    int slot = tid + u * 256;
    int row = slot >> 3, g = slot & 7;
    const float4* xp = (const float4*)(xg + row * D_ + g * 8);
    float4 x0 = xp[0], x1 = xp[1];
    bf16x8 o;
    o[0] = f2bf(x0.x); o[1] = f2bf(x0.y); o[2] = f2bf(x0.z); o[3] = f2bf(x0.w);
    o[4] = f2bf(x1.x); o[5] = f2bf(x1.y); o[6] = f2bf(x1.z); o[7] = f2bf(x1.w);
    xbuf[row * 8 + (g ^ (row & 7))] = o;
  }
  __syncthreads();

  if (t == 0) {
    f32x4 acc[4][2];
#pragma unroll
    for (int mt = 0; mt < 4; mt++)
#pragma unroll
      for (int nt = 0; nt < 2; nt++) { acc[mt][nt][0]=0.f; acc[mt][nt][1]=0.f; acc[mt][nt][2]=0.f; acc[mt][nt][3]=0.f; }
#pragma unroll
    for (int ks = 0; ks < 2; ++ks) {
      bf16x8 af[4], bfr[2];
#pragma unroll
      for (int mt = 0; mt < 4; ++mt) {
        int row = mt * 16 + l15;
        af[mt] = wbuf[row * 8 + ((ks * 4 + quad) ^ (row & 7))];
      }
#pragma unroll
      for (int nt = 0; nt < 2; ++nt) {
        int row = wave * 32 + nt * 16 + l15;
        bfr[nt] = xbuf[row * 8 + ((ks * 4 + quad) ^ (row & 7))];
      }
#pragma unroll
      for (int mt = 0; mt < 4; ++mt)
#pragma unroll
        for (int nt = 0; nt < 2; ++nt)
          acc[mt][nt] = __builtin_amdgcn_mfma_f32_16x16x32_bf16(
              af[mt], bfr[nt], acc[mt][nt], 0, 0, 0);
    }
    short* vb = vt + (bh * 64) * S_ + s0 + wave * 32;
#pragma unroll
    for (int mt = 0; mt < 4; ++mt)
#pragma unroll
      for (int nt = 0; nt < 2; ++nt)
#pragma unroll
        for (int r = 0; r < 4; ++r) {
          int e = mt * 16 + quad * 4 + r;
          int s = nt * 16 + l15;
          vb[e * S_ + s] = f2bf(acc[mt][nt][r]);
        }
  } else {
    f32x4 acc[2][4];
#pragma unroll
    for (int mt = 0; mt < 2; mt++)
#pragma unroll
      for (int nt = 0; nt < 4; nt++) { acc[mt][nt][0]=0.f; acc[mt][nt][1]=0.f; acc[mt][nt][2]=0.f; acc[mt][nt][3]=0.f; }
#pragma unroll
    for (int ks = 0; ks < 2; ++ks) {
      bf16x8 af[2], bfr[4];
#pragma unroll
      for (int mt = 0; mt < 2; ++mt) {
        int row = wave * 32 + mt * 16 + l15;
        af[mt] = xbuf[row * 8 + ((ks * 4 + quad) ^ (row & 7))];
      }
#pragma unroll
      for (int nt = 0; nt < 4; ++nt) {
        int row = nt * 16 + l15;
        bfr[nt] = wbuf[row * 8 + ((ks * 4 + quad) ^ (row & 7))];
      }
#pragma unroll
      for (int mt = 0; mt < 2; ++mt)
#pragma unroll
        for (int nt = 0; nt < 4; ++nt)
          acc[mt][nt] = __builtin_amdgcn_mfma_f32_16x16x32_bf16(
              af[mt], bfr[nt], acc[mt][nt], 0, 0, 0);
    }
    short* ob = ((t == 1) ? kp : qp) + (bh * S_ + s0 + wave * 32) * 64;
#pragma unroll
    for (int mt = 0; mt < 2; ++mt)
#pragma unroll
      for (int nt = 0; nt < 4; ++nt)
#pragma unroll
        for (int r = 0; r < 4; ++r) {
          int s = mt * 16 + quad * 4 + r;
          int e = nt * 16 + l15;
          ob[s * 64 + e] = f2bf(acc[mt][nt][r]);
        }
  }
}

// ---------------- Kernel 2: fused attention ----------------
// S^T = K*Q^T register-direct into PV (MFMA16); ones-column lsum; XCD-local
// heads. NEW: double-buffered K/V staging via global_load_lds DMA, ONE
// __syncthreads per kt -- loads for kt+1 are in flight during compute of kt.
__global__ __launch_bounds__(256) void attention(
    const short* __restrict__ qp, const short* __restrict__ kp,
    const short* __restrict__ vt, short* __restrict__ ao) {
  __shared__ bf16x8 kbuf[2][512];  // 2 x 8KB
  __shared__ bf16x8 vbuf[2][512];  // 2 x 8KB
  int bid = blockIdx.x;
  int qt = bid >> 6;   // 16 q-tiles of 128
  int bh = bid & 63;   // XCD = bid%8 = bh%8 -> whole head on one XCD
  int tid = threadIdx.x, wave = tid >> 6, lane = tid & 63;
  int quad = lane >> 4, l15 = lane & 15;

  // Q B-frags: 2 q-groups x (k 0..31 | 32..63), loaded once
  const short* qb = qp + (bh * S_ + qt * 128 + wave * 32 + l15) * 64;
  bf16x8 bq[2][2];
  bq[0][0] = *(const bf16x8*)(qb + quad * 8);
  bq[0][1] = *(const bf16x8*)(qb + 32 + quad * 8);
  bq[1][0] = *(const bf16x8*)(qb + 1024 + quad * 8);
  bq[1][1] = *(const bf16x8*)(qb + 1024 + 32 + quad * 8);

  f32x4 o[2][4];
#pragma unroll
  for (int g = 0; g < 2; g++)
#pragma unroll
    for (int dt = 0; dt < 4; dt++) { o[g][dt][0]=0.f; o[g][dt][1]=0.f; o[g][dt][2]=0.f; o[g][dt][3]=0.f; }
  f32x4 lacc[2];
  lacc[0][0]=0.f; lacc[0][1]=0.f; lacc[0][2]=0.f; lacc[0][3]=0.f;
  lacc[1][0]=0.f; lacc[1][1]=0.f; lacc[1][2]=0.f; lacc[1][3]=0.f;

  short one_bf = (short)0x3F80;
  bf16x4 ones;
  ones[0] = (l15 == 0) ? one_bf : (short)0;
  ones[1] = ones[0]; ones[2] = ones[0]; ones[3] = ones[0];

  const short* kg = kp + bh * S_ * 64;
  const short* vg = vt + bh * 64 * S_;

  // staging addresses (slot = tid + u*256, row = slot>>3, g = (slot&7)^(row&7))
  int rowA = tid >> 3, gA = (tid & 7) ^ (rowA & 7);
  int rowB = (tid + 256) >> 3, gB = (tid & 7) ^ (rowB & 7);
  const short* kA = kg + rowA * 64 + gA * 8;   // + kt*4096
  const short* kB = kg + rowB * 64 + gB * 8;
  const short* vA = vg + rowA * S_ + gA * 8;   // + kt*64
  const short* vB = vg + rowB * S_ + gB * 8;

  // prologue: DMA tile 0 into buffer 0
  gl_lds16(kA, &kbuf[0][tid]);
  gl_lds16(kB, &kbuf[0][tid + 256]);
  gl_lds16(vA, &vbuf[0][tid]);
  gl_lds16(vB, &vbuf[0][tid + 256]);

  int p = 0;
  for (int kt = 0; kt < 32; ++kt) {
    __syncthreads();  // vmcnt drain: buf[p] DMA complete; prev reads of buf[p^1] done
    {                 // issue DMA for next tile into the other buffer
      int ktn = (kt + 1) & 31;  // wrap (redundant last-iter load, in-bounds)
      gl_lds16(kA + ktn * 4096, &kbuf[p ^ 1][tid]);
      gl_lds16(kB + ktn * 4096, &kbuf[p ^ 1][tid + 256]);
      gl_lds16(vA + ktn * 64, &vbuf[p ^ 1][tid]);
      gl_lds16(vB + ktn * 64, &vbuf[p ^ 1][tid + 256]);
    }

    // ---- S^T = K*Q^T, then P = exp2(S^T) packed as PV A-frags ----
    bf16x4 pk[2][4];
#pragma unroll
    for (int nt = 0; nt < 4; ++nt) {
      int krow = nt * 16 + l15;
      bf16x8 ak0 = kbuf[p][krow * 8 + ((0 + quad) ^ (krow & 7))];
      bf16x8 ak1 = kbuf[p][krow * 8 + ((4 + quad) ^ (krow & 7))];
      f32x4 c0, c1;
      c0[0]=0.f; c0[1]=0.f; c0[2]=0.f; c0[3]=0.f;
      c1[0]=0.f; c1[1]=0.f; c1[2]=0.f; c1[3]=0.f;
      c0 = __builtin_amdgcn_mfma_f32_16x16x32_bf16(ak0, bq[0][0], c0, 0, 0, 0);
      c1 = __builtin_amdgcn_mfma_f32_16x16x32_bf16(ak0, bq[1][0], c1, 0, 0, 0);
      c0 = __builtin_amdgcn_mfma_f32_16x16x32_bf16(ak1, bq[0][1], c0, 0, 0, 0);
      c1 = __builtin_amdgcn_mfma_f32_16x16x32_bf16(ak1, bq[1][1], c1, 0, 0, 0);
      float e00 = fast_exp2(c0[0]), e01 = fast_exp2(c0[1]);
      float e02 = fast_exp2(c0[2]), e03 = fast_exp2(c0[3]);
      float e10 = fast_exp2(c1[0]), e11 = fast_exp2(c1[1]);
      float e12 = fast_exp2(c1[2]), e13 = fast_exp2(c1[3]);
      union { bf16x4 v; unsigned u[2]; } p0, p1;
      p0.u[0] = pack_trunc(e00, e01); p0.u[1] = pack_trunc(e02, e03);
      p1.u[0] = pack_trunc(e10, e11); p1.u[1] = pack_trunc(e12, e13);
      pk[0][nt] = p0.v; pk[1][nt] = p1.v;
    }
    // ---- PV + lsum (k-chunk c = 16 keys) ----
#pragma unroll
    for (int c = 0; c < 4; ++c) {
      lacc[0] = MFMA16(pk[0][c], ones, lacc[0]);
      lacc[1] = MFMA16(pk[1][c], ones, lacc[1]);
#pragma unroll
      for (int dt = 0; dt < 4; ++dt) {
        int d = dt * 16 + l15;
        int g0 = 2 * c + (quad >> 1);
        const short* vrow = (const short*)&vbuf[p][d * 8 + (g0 ^ (d & 7))];
        bf16x4 bv = *(const bf16x4*)(vrow + (quad & 1) * 4);
        o[0][dt] = MFMA16(pk[0][c], bv, o[0][dt]);
        o[1][dt] = MFMA16(pk[1][c], bv, o[1][dt]);
      }
    }
    p ^= 1;
  }

  // epilogue: lsum[q=quad*4+r] sits at lane (quad, l15==0), reg r
  int b = bh >> 4, h = bh & 15;
#pragma unroll
  for (int g = 0; g < 2; ++g) {
    float inv[4];
#pragma unroll
    for (int r = 0; r < 4; ++r) {
      float ls = __shfl(lacc[g][r], lane & 48, 64);
      inv[r] = fast_rcp(ls);
    }
#pragma unroll
    for (int dt = 0; dt < 4; ++dt)
#pragma unroll
      for (int r = 0; r < 4; ++r) {
        int srow = qt * 128 + wave * 32 + g * 16 + quad * 4 + r;
        ao[(b * S_ + srow) * D_ + h * 64 + dt * 16 + l15] =
            f2bf(o[g][dt][r] * inv[r]);
      }
  }
}

// ---------------- Kernel 3: output projection GEMM + bias ----------------
// Same DMA-dbuf single-barrier K-loop as attention.
__global__ __launch_bounds__(256) void outproj(const short* __restrict__ A,
                                               const short* __restrict__ Bw,
                                               const float* __restrict__ bo,
                                               float* __restrict__ out) {
  __shared__ bf16x8 sa[2][1024];  // 2 x 16KB
  __shared__ bf16x8 sb[2][1024];  // 2 x 16KB
  int bid = blockIdx.x;
  int m0 = (bid >> 3) * 128, n0 = (bid & 7) * 128;
  int tid = threadIdx.x, wave = tid >> 6, lane = tid & 63;
  int quad = lane >> 4, l15 = lane & 15;
  int wm = (wave >> 1) * 64, wn = (wave & 1) * 64;
  f32x4 acc[4][4];
#pragma unroll
  for (int mt = 0; mt < 4; mt++)
#pragma unroll
    for (int nt = 0; nt < 4; nt++) { acc[mt][nt][0]=0.f; acc[mt][nt][1]=0.f; acc[mt][nt][2]=0.f; acc[mt][nt][3]=0.f; }

  // staging addresses: slot = tid + u*256; row = slot>>3, g = (slot&7)^(row&7)
  const short* asrc[4];
  const short* bsrc[4];
#pragma unroll
  for (int u = 0; u < 4; ++u) {
    int slot = tid + u * 256;
    int row = slot >> 3, g = (slot & 7) ^ (row & 7);
    asrc[u] = A + (m0 + row) * 1024 + g * 8;    // + k0
    bsrc[u] = Bw + (n0 + row) * 1024 + g * 8;   // + k0
  }
  // prologue: DMA k-tile 0 into buffer 0
#pragma unroll
  for (int u = 0; u < 4; ++u) {
    gl_lds16(asrc[u], &sa[0][tid + u * 256]);
    gl_lds16(bsrc[u], &sb[0][tid + u * 256]);
  }

  int p = 0;
  for (int k0 = 0; k0 < 1024; k0 += 64) {
    __syncthreads();
    int kn = (k0 + 64) & 1023;  // wrap (redundant last-iter load, in-bounds)
#pragma unroll
    for (int u = 0; u < 4; ++u) {
      gl_lds16(asrc[u] + kn, &sa[p ^ 1][tid + u * 256]);
      gl_lds16(bsrc[u] + kn, &sb[p ^ 1][tid + u * 256]);
    }
#pragma unroll
    for (int ks = 0; ks < 2; ++ks) {
      bf16x8 af[4], bf[4];
#pragma unroll
      for (int mt = 0; mt < 4; ++mt) {
        int row = wm + mt * 16 + l15;
        af[mt] = sa[p][row * 8 + ((ks * 4 + quad) ^ (row & 7))];
      }
#pragma unroll
      for (int nt = 0; nt < 4; ++nt) {
        int row = wn + nt * 16 + l15;
        bf[nt] = sb[p][row * 8 + ((ks * 4 + quad) ^ (row & 7))];
      }
#pragma unroll
      for (int mt = 0; mt < 4; ++mt)
#pragma unroll
        for (int nt = 0; nt < 4; ++nt)
          acc[mt][nt] = __builtin_amdgcn_mfma_f32_16x16x32_bf16(
              af[mt], bf[nt], acc[mt][nt], 0, 0, 0);
    }
    p ^= 1;
  }
#pragma unroll
  for (int nt = 0; nt < 4; ++nt) {
    int n = n0 + wn + nt * 16 + l15;
    float bov = bo[n];
#pragma unroll
    for (int mt = 0; mt < 4; ++mt)
#pragma unroll
      for (int r = 0; r < 4; r++) {
        int m = m0 + wm + mt * 16 + quad * 4 + r;
        out[m * 1024 + n] = acc[mt][nt][r] + bov;
      }
  }
}

extern "C" void kernel_launch(void* const* d_in, const int* in_sizes, int n_in,
                              void* d_out, int out_size, void* d_ws,
                              size_t ws_size, hipStream_t stream) {
  const float* inpV = (const float*)d_in[0];
  const float* inpK = (const float*)d_in[1];
  const float* inpQ = (const float*)d_in[2];
  const float* Wv = (const float*)d_in[3];
  const float* Wk = (const float*)d_in[4];
  const float* Wq = (const float*)d_in[5];
  const float* Wo = (const float*)d_in[6];
  const float* bo = (const float*)d_in[7];
  float* out = (float*)d_out;

  char* ws = (char*)d_ws;
  short* vt = (short*)(ws);                       // 16MB  [B,H,64,S]
  short* kp = (short*)(ws + (16u << 20));         // 16MB  [B,H,S,64]
  short* qp = (short*)(ws + (32u << 20));         // 16MB  [B,H,S,64]
  short* ao = (short*)(ws + (48u << 20));         // 16MB  [B*S, D] bf16
  short* wob = (short*)(ws + (64u << 20));        // 2MB   Wo bf16

  wo_convert<<<dim3(512), dim3(256), 0, stream>>>(Wo, wob);
  qkv_proj2<<<dim3(3072), dim3(256), 0, stream>>>(inpV, inpK, inpQ, Wv, Wk, Wq,
                                                  vt, kp, qp);
  attention<<<dim3(1024), dim3(256), 0, stream>>>(qp, kp, vt, ao);
  outproj<<<dim3(512), dim3(256), 0, stream>>>(ao, wob, bo, out);
}

// Round 6
// 288.977 us; speedup vs baseline: 1.1323x; 1.0260x over previous
//
#include <hip/hip_runtime.h>
#include <hip/hip_bf16.h>

#define B_ 4
#define S_ 2048
#define D_ 1024
#define H_ 16
#define HD_ 64

typedef __attribute__((ext_vector_type(8))) short bf16x8;
typedef __attribute__((ext_vector_type(4))) short bf16x4;
typedef __attribute__((ext_vector_type(4))) float f32x4;

// legacy-K bf16 MFMA (v_mfma_f32_16x16x16_bf16): clang spelling is the
// gfx90a-era "_1k" name; valid on gfx950. NOT __has_builtin-guarded (that
// macro is target-sensitive and breaks the HIP host pass).
#define MFMA16(a, b, c) __builtin_amdgcn_mfma_f32_16x16x16bf16_1k(a, b, c, 0, 0, 0)
#define MFMA32(a, b, c) __builtin_amdgcn_mfma_f32_16x16x32_bf16(a, b, c, 0, 0, 0)

__device__ __forceinline__ float fast_exp2(float x) {
#if __has_builtin(__builtin_amdgcn_exp2f)
  return __builtin_amdgcn_exp2f(x);
#else
  return exp2f(x);
#endif
}

__device__ __forceinline__ float fast_rcp(float x) {
#if __has_builtin(__builtin_amdgcn_rcpf)
  return __builtin_amdgcn_rcpf(x);
#else
  return 1.0f / x;
#endif
}

__device__ __forceinline__ short f2bf(float x) {
  union { float f; unsigned u; } v; v.f = x;
  unsigned r = (v.u + 0x7fffu + ((v.u >> 16) & 1u)) >> 16;
  return (short)(r & 0xffffu);
}

// single v_perm_b32 truncation pack: dst = (hi16(b)<<16)|hi16(a).
// Truncation bias cancels in softmax ratio (lsum sums the SAME truncated P).
__device__ __forceinline__ unsigned pack_hi16(float a, float b) {
  union { float f; unsigned u; } ua, ub; ua.f = a; ub.f = b;
  return __builtin_amdgcn_perm(ub.u, ua.u, 0x07060302u);
}

// async global->LDS DMA, 16 B per lane; LDS dest = wave-uniform base + lane*16.
__device__ __forceinline__ void gl_lds16(const short* g, void* l) {
  __builtin_amdgcn_global_load_lds(
      (const __attribute__((address_space(1))) unsigned*)(const void*)g,
      (__attribute__((address_space(3))) unsigned*)l, 16, 0, 0);
}

// ---------------- Kernel 0: convert Wo (fp32 -> bf16) ----------------
__global__ __launch_bounds__(256) void wo_convert(const float* __restrict__ Wo,
                                                  short* __restrict__ wob) {
  int i = blockIdx.x * blockDim.x + threadIdx.x;
  const float4* src = (const float4*)Wo + i * 2;
  float4 a = src[0], b = src[1];
  bf16x8 o;
  o[0] = f2bf(a.x); o[1] = f2bf(a.y); o[2] = f2bf(a.z); o[3] = f2bf(a.w);
  o[4] = f2bf(b.x); o[5] = f2bf(b.y); o[6] = f2bf(b.z); o[7] = f2bf(b.w);
  ((bf16x8*)wob)[i] = o;
}

// ---------------- Kernel 1: QKV projections via MFMA ----------------
__global__ __launch_bounds__(256) void qkv_proj2(
    const float* __restrict__ inpV, const float* __restrict__ inpK,
    const float* __restrict__ inpQ, const float* __restrict__ Wv,
    const float* __restrict__ Wk, const float* __restrict__ Wq,
    short* __restrict__ vt, short* __restrict__ kp, short* __restrict__ qp) {
  __shared__ bf16x8 xbuf[1024];  // 128 rows x 8 groups (16KB), g^=row&7
  __shared__ bf16x8 wbuf[512];   // 64 rows x 8 groups (8KB), g^=row&7
  int bid = blockIdx.x;
  int t = bid >> 10;           // 1024 blocks per tensor
  int bh = (bid >> 4) & 63;    // b*16+h
  int st = bid & 15;
  int b = bh >> 4, h = bh & 15;
  int s0 = st * 128;
  int tid = threadIdx.x, wave = tid >> 6, lane = tid & 63;
  int quad = lane >> 4, l15 = lane & 15;
  const float* inp = (t == 0) ? inpV : (t == 1) ? inpK : inpQ;
  const float* W = (t == 0) ? Wv : (t == 1) ? Wk : Wq;
  // fold score scale AND log2(e) into Wq (attention uses exp2)
  float wscale = (t == 2) ? (0.03125f * 1.4426950408889634f) : 1.0f;

#pragma unroll
  for (int u = 0; u < 2; ++u) {
    int slot = tid + u * 256;
    int row = slot >> 3, g = slot & 7;
    const float4* wp = (const float4*)(W + row * 64 + g * 8);
    float4 w0 = wp[0], w1 = wp[1];
    bf16x8 o;
    o[0] = f2bf(w0.x * wscale); o[1] = f2bf(w0.y * wscale);
    o[2] = f2bf(w0.z * wscale); o[3] = f2bf(w0.w * wscale);
    o[4] = f2bf(w1.x * wscale); o[5] = f2bf(w1.y * wscale);
    o[6] = f2bf(w1.z * wscale); o[7] = f2bf(w1.w * wscale);
    wbuf[row * 8 + (g ^ (row & 7))] = o;
  }
  const float* xg = inp + (b * S_ + s0) * D_ + h * HD_;
#pragma unroll
  for (int u = 0; u < 4; ++u) {
    int slot = tid + u * 256;
    int row = slot >> 3, g = slot & 7;
    const float4* xp = (const float4*)(xg + row * D_ + g * 8);
    float4 x0 = xp[0], x1 = xp[1];
    bf16x8 o;
    o[0] = f2bf(x0.x); o[1] = f2bf(x0.y); o[2] = f2bf(x0.z); o[3] = f2bf(x0.w);
    o[4] = f2bf(x1.x); o[5] = f2bf(x1.y); o[6] = f2bf(x1.z); o[7] = f2bf(x1.w);
    xbuf[row * 8 + (g ^ (row & 7))] = o;
  }
  __syncthreads();

  if (t == 0) {
    f32x4 acc[4][2];
#pragma unroll
    for (int mt = 0; mt < 4; mt++)
#pragma unroll
      for (int nt = 0; nt < 2; nt++) { acc[mt][nt][0]=0.f; acc[mt][nt][1]=0.f; acc[mt][nt][2]=0.f; acc[mt][nt][3]=0.f; }
#pragma unroll
    for (int ks = 0; ks < 2; ++ks) {
      bf16x8 af[4], bfr[2];
#pragma unroll
      for (int mt = 0; mt < 4; ++mt) {
        int row = mt * 16 + l15;
        af[mt] = wbuf[row * 8 + ((ks * 4 + quad) ^ (row & 7))];
      }
#pragma unroll
      for (int nt = 0; nt < 2; ++nt) {
        int row = wave * 32 + nt * 16 + l15;
        bfr[nt] = xbuf[row * 8 + ((ks * 4 + quad) ^ (row & 7))];
      }
#pragma unroll
      for (int mt = 0; mt < 4; ++mt)
#pragma unroll
        for (int nt = 0; nt < 2; ++nt)
          acc[mt][nt] = MFMA32(af[mt], bfr[nt], acc[mt][nt]);
    }
    short* vb = vt + (bh * 64) * S_ + s0 + wave * 32;
#pragma unroll
    for (int mt = 0; mt < 4; ++mt)
#pragma unroll
      for (int nt = 0; nt < 2; ++nt)
#pragma unroll
        for (int r = 0; r < 4; ++r) {
          int e = mt * 16 + quad * 4 + r;
          int s = nt * 16 + l15;
          vb[e * S_ + s] = f2bf(acc[mt][nt][r]);
        }
  } else {
    f32x4 acc[2][4];
#pragma unroll
    for (int mt = 0; mt < 2; mt++)
#pragma unroll
      for (int nt = 0; nt < 4; nt++) { acc[mt][nt][0]=0.f; acc[mt][nt][1]=0.f; acc[mt][nt][2]=0.f; acc[mt][nt][3]=0.f; }
#pragma unroll
    for (int ks = 0; ks < 2; ++ks) {
      bf16x8 af[2], bfr[4];
#pragma unroll
      for (int mt = 0; mt < 2; ++mt) {
        int row = wave * 32 + mt * 16 + l15;
        af[mt] = xbuf[row * 8 + ((ks * 4 + quad) ^ (row & 7))];
      }
#pragma unroll
      for (int nt = 0; nt < 4; ++nt) {
        int row = nt * 16 + l15;
        bfr[nt] = wbuf[row * 8 + ((ks * 4 + quad) ^ (row & 7))];
      }
#pragma unroll
      for (int mt = 0; mt < 2; ++mt)
#pragma unroll
        for (int nt = 0; nt < 4; ++nt)
          acc[mt][nt] = MFMA32(af[mt], bfr[nt], acc[mt][nt]);
    }
    short* ob = ((t == 1) ? kp : qp) + (bh * S_ + s0 + wave * 32) * 64;
#pragma unroll
    for (int mt = 0; mt < 2; ++mt)
#pragma unroll
      for (int nt = 0; nt < 4; ++nt)
#pragma unroll
        for (int r = 0; r < 4; ++r) {
          int s = mt * 16 + quad * 4 + r;
          int e = nt * 16 + l15;
          ob[s * 64 + e] = f2bf(acc[mt][nt][r]);
        }
  }
}

// ---------------- Kernel 2: fused attention ----------------
// 128-thread blocks (2 waves x 32q), 32-key tiles, grid 2048 -> 8
// independently-phased blocks/CU. Per-nt fused QK->exp->pack->PV for fine
// MFMA/VALU interleave. DMA dbuf, one barrier per kt. S^T trick, ones-lsum.
__global__ __launch_bounds__(128, 4) void attention(
    const short* __restrict__ qp, const short* __restrict__ kp,
    const short* __restrict__ vt, short* __restrict__ ao) {
  __shared__ bf16x8 kbuf[2][256];  // 32 krows x 8 groups (4KB each)
  __shared__ bf16x8 vbuf[2][256];  // 64 drows x 4 groups (4KB each)
  int bid = blockIdx.x;
  int qt = bid >> 6;   // 32 q-tiles of 64
  int bh = bid & 63;   // XCD = bid%8 = bh%8 -> whole head on one XCD
  int tid = threadIdx.x, wave = tid >> 6, lane = tid & 63;
  int quad = lane >> 4, l15 = lane & 15;

  // Q B-frags: 2 q-groups x (k 0..31 | 32..63), loaded once
  const short* qb = qp + (bh * S_ + qt * 64 + wave * 32 + l15) * 64;
  bf16x8 bq[2][2];
  bq[0][0] = *(const bf16x8*)(qb + quad * 8);
  bq[0][1] = *(const bf16x8*)(qb + 32 + quad * 8);
  bq[1][0] = *(const bf16x8*)(qb + 1024 + quad * 8);
  bq[1][1] = *(const bf16x8*)(qb + 1024 + 32 + quad * 8);

  const f32x4 fzero = {0.f, 0.f, 0.f, 0.f};
  f32x4 o[2][4];
#pragma unroll
  for (int g = 0; g < 2; g++)
#pragma unroll
    for (int dt = 0; dt < 4; dt++) o[g][dt] = fzero;
  f32x4 lacc[2];
  lacc[0] = fzero; lacc[1] = fzero;

  short one_bf = (short)0x3F80;
  bf16x4 ones;
  ones[0] = (l15 == 0) ? one_bf : (short)0;
  ones[1] = ones[0]; ones[2] = ones[0]; ones[3] = ones[0];

  const short* kg = kp + bh * S_ * 64;
  const short* vg = vt + bh * 64 * S_;

  // staging addresses. K: slot=tid+u*128, row=slot>>3 (0..31), g=slot&7,
  // swizzle g^(row&7). V: row=slot>>2 (0..63), g=slot&3, swizzle g^(row&3).
  int krow0 = tid >> 3, kg0 = (tid & 7) ^ (krow0 & 7);
  int krow1 = (tid + 128) >> 3, kg1 = (tid & 7) ^ (krow1 & 7);
  const short* kA = kg + krow0 * 64 + kg0 * 8;   // + kt*2048
  const short* kB = kg + krow1 * 64 + kg1 * 8;
  int vrow0 = tid >> 2, vg0 = (tid & 3) ^ (vrow0 & 3);
  int vrow1 = (tid + 128) >> 2, vg1 = (tid & 3) ^ (vrow1 & 3);
  const short* vA = vg + vrow0 * S_ + vg0 * 8;   // + kt*32
  const short* vB = vg + vrow1 * S_ + vg1 * 8;

  // prologue: DMA tile 0 into buffer 0
  gl_lds16(kA, &kbuf[0][tid]);
  gl_lds16(kB, &kbuf[0][tid + 128]);
  gl_lds16(vA, &vbuf[0][tid]);
  gl_lds16(vB, &vbuf[0][tid + 128]);

  int p = 0;
  for (int kt = 0; kt < 64; ++kt) {
    __syncthreads();  // buf[p] DMA complete; prev reads of buf[p^1] done
    int ktn = (kt + 1) & 63;  // wrap: redundant in-bounds last-iter load
    gl_lds16(kA + ktn * 2048, &kbuf[p ^ 1][tid]);
    gl_lds16(kB + ktn * 2048, &kbuf[p ^ 1][tid + 128]);
    gl_lds16(vA + ktn * 32, &vbuf[p ^ 1][tid]);
    gl_lds16(vB + ktn * 32, &vbuf[p ^ 1][tid + 128]);

#pragma unroll
    for (int nt = 0; nt < 2; ++nt) {
      // ---- S^T = K*Q^T for 16 keys x 32 q ----
      int krow = nt * 16 + l15;
      bf16x8 ak0 = kbuf[p][krow * 8 + ((0 + quad) ^ (krow & 7))];
      bf16x8 ak1 = kbuf[p][krow * 8 + ((4 + quad) ^ (krow & 7))];
      f32x4 c0 = MFMA32(ak0, bq[0][0], fzero);
      f32x4 c1 = MFMA32(ak0, bq[1][0], fzero);
      c0 = MFMA32(ak1, bq[0][1], c0);
      c1 = MFMA32(ak1, bq[1][1], c1);
      // ---- P = exp2(S^T), v_perm pack into PV A-frags ----
      float e00 = fast_exp2(c0[0]), e01 = fast_exp2(c0[1]);
      float e02 = fast_exp2(c0[2]), e03 = fast_exp2(c0[3]);
      float e10 = fast_exp2(c1[0]), e11 = fast_exp2(c1[1]);
      float e12 = fast_exp2(c1[2]), e13 = fast_exp2(c1[3]);
      union { bf16x4 v; unsigned u[2]; } p0, p1;
      p0.u[0] = pack_hi16(e00, e01); p0.u[1] = pack_hi16(e02, e03);
      p1.u[0] = pack_hi16(e10, e11); p1.u[1] = pack_hi16(e12, e13);
      // ---- lsum + PV for this 16-key chunk ----
      lacc[0] = MFMA16(p0.v, ones, lacc[0]);
      lacc[1] = MFMA16(p1.v, ones, lacc[1]);
#pragma unroll
      for (int dt = 0; dt < 4; ++dt) {
        int d = dt * 16 + l15;
        int g0 = 2 * nt + (quad >> 1);
        const short* vrow = (const short*)&vbuf[p][d * 4 + (g0 ^ (d & 3))];
        bf16x4 bv = *(const bf16x4*)(vrow + (quad & 1) * 4);
        o[0][dt] = MFMA16(p0.v, bv, o[0][dt]);
        o[1][dt] = MFMA16(p1.v, bv, o[1][dt]);
      }
    }
    p ^= 1;
  }

  // epilogue: lsum[q=quad*4+r] sits at lane (quad, l15==0), reg r
  int b = bh >> 4, h = bh & 15;
#pragma unroll
  for (int g = 0; g < 2; ++g) {
    float inv[4];
#pragma unroll
    for (int r = 0; r < 4; ++r) {
      float ls = __shfl(lacc[g][r], lane & 48, 64);
      inv[r] = fast_rcp(ls);
    }
#pragma unroll
    for (int dt = 0; dt < 4; ++dt)
#pragma unroll
      for (int r = 0; r < 4; ++r) {
        int srow = qt * 64 + wave * 32 + g * 16 + quad * 4 + r;
        ao[(b * S_ + srow) * D_ + h * 64 + dt * 16 + l15] =
            f2bf(o[g][dt][r] * inv[r]);
      }
  }
}

// ---------------- Kernel 3: output projection GEMM + bias ----------------
// DMA-dbuf single-barrier K-loop.
__global__ __launch_bounds__(256) void outproj(const short* __restrict__ A,
                                               const short* __restrict__ Bw,
                                               const float* __restrict__ bo,
                                               float* __restrict__ out) {
  __shared__ bf16x8 sa[2][1024];  // 2 x 16KB
  __shared__ bf16x8 sb[2][1024];  // 2 x 16KB
  int bid = blockIdx.x;
  int m0 = (bid >> 3) * 128, n0 = (bid & 7) * 128;
  int tid = threadIdx.x, wave = tid >> 6, lane = tid & 63;
  int quad = lane >> 4, l15 = lane & 15;
  int wm = (wave >> 1) * 64, wn = (wave & 1) * 64;
  f32x4 acc[4][4];
#pragma unroll
  for (int mt = 0; mt < 4; mt++)
#pragma unroll
    for (int nt = 0; nt < 4; nt++) { acc[mt][nt][0]=0.f; acc[mt][nt][1]=0.f; acc[mt][nt][2]=0.f; acc[mt][nt][3]=0.f; }

  const short* asrc[4];
  const short* bsrc[4];
#pragma unroll
  for (int u = 0; u < 4; ++u) {
    int slot = tid + u * 256;
    int row = slot >> 3, g = (slot & 7) ^ (row & 7);
    asrc[u] = A + (m0 + row) * 1024 + g * 8;
    bsrc[u] = Bw + (n0 + row) * 1024 + g * 8;
  }
#pragma unroll
  for (int u = 0; u < 4; ++u) {
    gl_lds16(asrc[u], &sa[0][tid + u * 256]);
    gl_lds16(bsrc[u], &sb[0][tid + u * 256]);
  }

  int p = 0;
  for (int k0 = 0; k0 < 1024; k0 += 64) {
    __syncthreads();
    int kn = (k0 + 64) & 1023;
#pragma unroll
    for (int u = 0; u < 4; ++u) {
      gl_lds16(asrc[u] + kn, &sa[p ^ 1][tid + u * 256]);
      gl_lds16(bsrc[u] + kn, &sb[p ^ 1][tid + u * 256]);
    }
#pragma unroll
    for (int ks = 0; ks < 2; ++ks) {
      bf16x8 af[4], bf[4];
#pragma unroll
      for (int mt = 0; mt < 4; ++mt) {
        int row = wm + mt * 16 + l15;
        af[mt] = sa[p][row * 8 + ((ks * 4 + quad) ^ (row & 7))];
      }
#pragma unroll
      for (int nt = 0; nt < 4; ++nt) {
        int row = wn + nt * 16 + l15;
        bf[nt] = sb[p][row * 8 + ((ks * 4 + quad) ^ (row & 7))];
      }
#pragma unroll
      for (int mt = 0; mt < 4; ++mt)
#pragma unroll
        for (int nt = 0; nt < 4; ++nt)
          acc[mt][nt] = MFMA32(af[mt], bf[nt], acc[mt][nt]);
    }
    p ^= 1;
  }
#pragma unroll
  for (int nt = 0; nt < 4; ++nt) {
    int n = n0 + wn + nt * 16 + l15;
    float bov = bo[n];
#pragma unroll
    for (int mt = 0; mt < 4; ++mt)
#pragma unroll
      for (int r = 0; r < 4; r++) {
        int m = m0 + wm + mt * 16 + quad * 4 + r;
        out[m * 1024 + n] = acc[mt][nt][r] + bov;
      }
  }
}

extern "C" void kernel_launch(void* const* d_in, const int* in_sizes, int n_in,
                              void* d_out, int out_size, void* d_ws,
                              size_t ws_size, hipStream_t stream) {
  const float* inpV = (const float*)d_in[0];
  const float* inpK = (const float*)d_in[1];
  const float* inpQ = (const float*)d_in[2];
  const float* Wv = (const float*)d_in[3];
  const float* Wk = (const float*)d_in[4];
  const float* Wq = (const float*)d_in[5];
  const float* Wo = (const float*)d_in[6];
  const float* bo = (const float*)d_in[7];
  float* out = (float*)d_out;

  char* ws = (char*)d_ws;
  short* vt = (short*)(ws);                       // 16MB  [B,H,64,S]
  short* kp = (short*)(ws + (16u << 20));         // 16MB  [B,H,S,64]
  short* qp = (short*)(ws + (32u << 20));         // 16MB  [B,H,S,64]
  short* ao = (short*)(ws + (48u << 20));         // 16MB  [B*S, D] bf16
  short* wob = (short*)(ws + (64u << 20));        // 2MB   Wo bf16

  wo_convert<<<dim3(512), dim3(256), 0, stream>>>(Wo, wob);
  qkv_proj2<<<dim3(3072), dim3(256), 0, stream>>>(inpV, inpK, inpQ, Wv, Wk, Wq,
                                                  vt, kp, qp);
  attention<<<dim3(2048), dim3(128), 0, stream>>>(qp, kp, vt, ao);
  outproj<<<dim3(512), dim3(256), 0, stream>>>(ao, wob, bo, out);
}